// Round 13
// baseline (5774.557 us; speedup 1.0000x reference)
//
#include <hip/hip_runtime.h>
#include <hip/hip_bf16.h>

#pragma clang fp contract(off)

#define NTH   1024      // 16 waves = 4 waves/EU = exactly 1 block/CU
#define PPT   16        // NTH*PPT == NPTS
#define NPTS  16384
#define BATCH 16
#define CFEAT 128
#define SMAX  4096
#define NWAVE (NTH / 64)

typedef __attribute__((ext_vector_type(2))) float f32x2;

__device__ __forceinline__ f32x2 pin2(f32x2 v) {
    asm volatile("" : "+v"(v));
    return v;
}

// ---------------------------------------------------------------------------
// FPS kernel, one block per batch.
// CORRECTNESS INVARIANTS (proven r0-r12; do not change):
//   * d  = fma(dz,dz, fma(dx,dx, dy*dy))      [XLA contraction form]
//   * md = fminf(D[k], d)
//   * argmax: max value, ties -> LOWEST original point index
//   * emission: idx[t] = last BEFORE the update pass
// r13 machinery:
//   * amdgpu_waves_per_eu(4,4): r10-r12 proved launch_bounds' 2nd arg is only
//     a MINIMUM - the allocator maximizes occupancy (targets ~48 arch VGPRs)
//     and AGPR-parks the state (VGPR_Count 48-84, ~5 v_accvgpr moves/pt).
//     Pinning min=max=4 grants 512/4=128 arch VGPRs: state (64) + temps fit.
//   * v_pk_{add,mul,fma}_f32 packed math (inline asm): 2 points/inst for the
//     distance chain. Per-half ops are IEEE-exact f32, and X+(-px) == X-px
//     bitwise, so d is bit-identical to the scalar form.
//   * DPP wave64 max-reduce (row_shr 1/2/4/8, bcast15, bcast31, readlane 63):
//     7 VALU ops replace the 6-chained-ds_bpermute butterfly (~190->~40cyc).
//     bound_ctrl 0-fill is identity for nonneg float bits under u32 max.
//   * contiguous mapping gi = tid*16+k -> value-only loop; candidates rescan
//     + atomicMin rotating 4-slot LDS cell (r10); uniform L2 coord fetch.
// ---------------------------------------------------------------------------
template <bool FUSED>
__global__ __launch_bounds__(NTH)
__attribute__((amdgpu_waves_per_eu(4, 4)))
void fps_kernel(const float* __restrict__ xyz,
                const float* __restrict__ x,
                int* __restrict__ idx_out,
                float* __restrict__ out,
                int S) {
    const int b    = blockIdx.x;
    const int tid  = threadIdx.x;
    const int wid  = tid >> 6;
    const int lane = tid & 63;
    const float* __restrict__ xb = xyz + (size_t)b * 3 * NPTS;

    // read-only coords as aligned f32 pairs (for VOP3P); D scalar (no pairing)
    f32x2 X2[PPT / 2], Y2[PPT / 2], Z2[PPT / 2];
    float D[PPT];
    const int p0 = tid * PPT;
    {
        const f32x2* __restrict__ xp = (const f32x2*)(xb + p0);
        const f32x2* __restrict__ yp = (const f32x2*)(xb + NPTS + p0);
        const f32x2* __restrict__ zp = (const f32x2*)(xb + 2 * NPTS + p0);
#pragma unroll
        for (int j = 0; j < PPT / 2; ++j) {
            X2[j] = pin2(xp[j]);
            Y2[j] = pin2(yp[j]);
            Z2[j] = pin2(zp[j]);
            D[2 * j] = INFINITY;
            D[2 * j + 1] = INFINITY;
        }
    }

    __shared__ unsigned s_vmax[NWAVE];
    __shared__ unsigned s_gi[4];
    __shared__ int      s_idx[FUSED ? SMAX : 1];

    if (tid == 0) { s_gi[0] = s_gi[1] = s_gi[2] = s_gi[3] = 0xFFFFFFFFu; }
    __syncthreads();

    int   last = 0;
    float px = xb[0], py = xb[NPTS], pz = xb[2 * NPTS];

    for (int t = 0; t < S; ++t) {
        if (tid == 0) {
            if (FUSED) s_idx[t] = last;
            else       idx_out[b * S + t] = last;
        }

        // broadcast negated pick coords into packed pairs
        f32x2 npx2, npy2, npz2;
        npx2.x = -px; npx2.y = -px;
        npy2.x = -py; npy2.y = -py;
        npz2.x = -pz; npz2.y = -pz;

        // ---- update pass: packed distance chain, scalar min/max
        float best = -INFINITY;
#pragma unroll
        for (int j = 0; j < PPT / 2; ++j) {
            f32x2 dx2, dy2, dz2, sq, f1, d2;
            asm("v_pk_add_f32 %0, %1, %2" : "=v"(dx2) : "v"(X2[j]), "v"(npx2));
            asm("v_pk_add_f32 %0, %1, %2" : "=v"(dy2) : "v"(Y2[j]), "v"(npy2));
            asm("v_pk_add_f32 %0, %1, %2" : "=v"(dz2) : "v"(Z2[j]), "v"(npz2));
            asm("v_pk_mul_f32 %0, %1, %1" : "=v"(sq)  : "v"(dy2));
            asm("v_pk_fma_f32 %0, %1, %1, %2" : "=v"(f1) : "v"(dx2), "v"(sq));
            asm("v_pk_fma_f32 %0, %1, %1, %2" : "=v"(d2) : "v"(dz2), "v"(f1));
            const float mlo = fminf(D[2 * j],     d2.x);
            const float mhi = fminf(D[2 * j + 1], d2.y);
            D[2 * j]     = mlo;
            D[2 * j + 1] = mhi;
            best = fmaxf(best, fmaxf(mlo, mhi));
        }
        const unsigned mybits = __float_as_uint(best);  // d>=0: u32 order == f32 order

        // ---- wave max via DPP (rocPRIM wave64 pattern), result uniform
        unsigned red = mybits;
#define DPP_MAX_STEP(CTRL)                                                     \
        {                                                                      \
            unsigned tpp = (unsigned)__builtin_amdgcn_update_dpp(              \
                0, (int)red, (CTRL), 0xf, 0xf, true);                          \
            red = (tpp > red) ? tpp : red;                                     \
        }
        DPP_MAX_STEP(0x111)   // row_shr:1
        DPP_MAX_STEP(0x112)   // row_shr:2
        DPP_MAX_STEP(0x114)   // row_shr:4
        DPP_MAX_STEP(0x118)   // row_shr:8
        DPP_MAX_STEP(0x142)   // row_bcast:15
        DPP_MAX_STEP(0x143)   // row_bcast:31
#undef DPP_MAX_STEP
        const unsigned wmax = (unsigned)__builtin_amdgcn_readlane((int)red, 63);

        if (lane == 0) s_vmax[wid] = wmax;
        if (tid == 0)  s_gi[(t + 2) & 3] = 0xFFFFFFFFu;   // rotate-init future slot
        __syncthreads();                                   // B1

        // ---- block max (broadcast LDS reads)
        unsigned vb = s_vmax[0];
#pragma unroll
        for (int w = 1; w < NWAVE; ++w) {
            const unsigned vw = s_vmax[w];
            vb = (vw > vb) ? vw : vb;
        }

        // ---- index resolve: only candidate lanes (~1-2 per block) pay
        if (mybits == vb) {
            int kk = PPT - 1;
#pragma unroll
            for (int j = PPT / 2 - 1; j >= 0; --j) {       // descending k; ends lowest
                if (__float_as_uint(D[2 * j + 1]) == mybits) kk = 2 * j + 1;
                if (__float_as_uint(D[2 * j])     == mybits) kk = 2 * j;
            }
            atomicMin(&s_gi[t & 3], (unsigned)(p0 + kk));
        }
        __syncthreads();                                   // B2

        last = (int)s_gi[t & 3];
        // uniform fetch of the new pick's coordinates (L2-resident)
        px = xb[last];
        py = xb[NPTS + last];
        pz = xb[2 * NPTS + last];
    }

    if (FUSED) {
        __syncthreads();
        for (int i = tid; i < CFEAT * S; i += NTH) {
            const int c = i / S, s = i - c * S;
            const long r = (long)b * CFEAT + c;
            out[r * S + s] = x[r * NPTS + s_idx[s]];
        }
        const long base = (long)BATCH * CFEAT * S;
        for (int i = tid; i < 3 * S; i += NTH) {
            const int c = i / S, s = i - c * S;
            const long r = (long)b * 3 + c;
            out[base + r * S + s] = xyz[r * NPTS + s_idx[s]];
        }
    }
}

// ---------------------------------------------------------------------------
// Gather kernel (full-chip): out = concat( x_s [B][C][S], xyz_s [B][3][S] ).
// ---------------------------------------------------------------------------
__global__ void gather_kernel(const float* __restrict__ x,
                              const float* __restrict__ xyz,
                              const int* __restrict__ idx,
                              float* __restrict__ out,
                              int S) {
    const long nxs   = (long)BATCH * CFEAT * S;
    const long total = nxs + (long)BATCH * 3 * S;
    for (long i = (long)blockIdx.x * blockDim.x + threadIdx.x; i < total;
         i += (long)gridDim.x * blockDim.x) {
        if (i < nxs) {
            const int s  = (int)(i % S);
            const long r = i / S;            // b*C + c
            const int b  = (int)(r / CFEAT);
            const int p  = idx[b * S + s];
            out[i] = x[r * NPTS + p];
        } else {
            const long j = i - nxs;
            const int s  = (int)(j % S);
            const long r = j / S;            // b*3 + c
            const int b  = (int)(r / 3);
            const int p  = idx[b * S + s];
            out[i] = xyz[r * NPTS + p];
        }
    }
}

extern "C" void kernel_launch(void* const* d_in, const int* in_sizes, int n_in,
                              void* d_out, int out_size, void* d_ws, size_t ws_size,
                              hipStream_t stream) {
    const float* x   = nullptr;   // [B, C, N]
    const float* xyz = nullptr;   // [B, 3, N]
    for (int i = 0; i < n_in; ++i) {
        if (in_sizes[i] == BATCH * CFEAT * NPTS)  x   = (const float*)d_in[i];
        else if (in_sizes[i] == BATCH * 3 * NPTS) xyz = (const float*)d_in[i];
    }
    float* out = (float*)d_out;
    const int S = out_size / (BATCH * (CFEAT + 3));

    const size_t need = (size_t)BATCH * (size_t)S * sizeof(int);
    if (ws_size >= need && d_ws != nullptr) {
        int* idx = (int*)d_ws;
        fps_kernel<false><<<BATCH, NTH, 0, stream>>>(xyz, nullptr, idx, nullptr, S);
        gather_kernel<<<2048, 256, 0, stream>>>(x, xyz, idx, out, S);
    } else {
        fps_kernel<true><<<BATCH, NTH, 0, stream>>>(xyz, x, nullptr, out, S);
    }
}